// Round 1
// baseline (895.050 us; speedup 1.0000x reference)
//
#include <hip/hip_runtime.h>
#include <math.h>

// Problem constants
constexpr int Bb   = 16;
constexpr int Cc   = 256;
constexpr int Hh   = 128;
constexpr int Ww   = 128;
constexpr int NPIX = Hh * Ww;     // 16384
constexpr int RED  = 64;
constexpr int MID  = 32;
constexpr float SCALE = 0.35355339059327373f;  // 8^-0.5

// ---------------------------------------------------------------------------
// Kernel P: fold BN_in into in_proj, fold sigmoid(alpha)*BN_out into out_proj
// ---------------------------------------------------------------------------
__global__ __launch_bounds__(256) void prep_kernel(
    const float* __restrict__ bn_in_gamma, const float* __restrict__ bn_in_beta,
    const float* __restrict__ bn_in_mean,  const float* __restrict__ bn_in_var,
    const float* __restrict__ in_proj_w,
    const float* __restrict__ out_proj_w,
    const float* __restrict__ bn_out_gamma, const float* __restrict__ bn_out_beta,
    const float* __restrict__ bn_out_mean,  const float* __restrict__ bn_out_var,
    const float* __restrict__ alpha,
    float* __restrict__ Weff_in,  float* __restrict__ beff_in,
    float* __restrict__ Weff_out, float* __restrict__ beff_out) {
  int idx = blockIdx.x * 256 + threadIdx.x;
  float s = 1.0f / (1.0f + __expf(-alpha[0]));
  if (idx < RED * Cc) {  // Weff_in[o][c]
    int c = idx & 255;
    float inv = bn_in_gamma[c] * rsqrtf(bn_in_var[c] + 1e-5f);
    Weff_in[idx] = in_proj_w[idx] * inv;
  }
  if (idx < Cc * RED) {  // Weff_out[co][r]
    int co = idx >> 6;
    float inv2 = bn_out_gamma[co] * rsqrtf(bn_out_var[co] + 1e-5f);
    Weff_out[idx] = s * inv2 * out_proj_w[idx];
  }
  if (idx < RED) {       // beff_in[o] = sum_c W[o,c]*(beta - mean*inv)
    float acc = 0.f;
    for (int c = 0; c < Cc; c++) {
      float inv = bn_in_gamma[c] * rsqrtf(bn_in_var[c] + 1e-5f);
      acc += in_proj_w[idx * Cc + c] * (bn_in_beta[c] - bn_in_mean[c] * inv);
    }
    beff_in[idx] = acc;
  }
  if (idx < Cc) {        // beff_out[co]
    float inv2 = bn_out_gamma[idx] * rsqrtf(bn_out_var[idx] + 1e-5f);
    beff_out[idx] = s * (bn_out_beta[idx] - bn_out_mean[idx] * inv2);
  }
}

// ---------------------------------------------------------------------------
// Kernel A: x_red[b,o,p] = beff_in[o] + sum_c Weff_in[o,c]*x[b,c,p]
// Tile: 64 outputs x 128 positions per block, K chunked by 32.
// ---------------------------------------------------------------------------
__global__ __launch_bounds__(256) void inproj_kernel(
    const float* __restrict__ x, const float* __restrict__ Weff,
    const float* __restrict__ beff, float* __restrict__ xred) {
  __shared__ float Xs[32][128];
  __shared__ float Ws[32][64];
  const int b  = blockIdx.y;
  const int p0 = blockIdx.x * 128;
  const int tid = threadIdx.x;
  const int tx = tid & 31;          // position quad: p = p0 + tx*4
  const int ty = tid >> 5;          // output group: o = ty*8 .. +7
  const int o0 = ty * 8;

  float acc[8][4];
  #pragma unroll
  for (int i = 0; i < 8; i++) {
    float bia = beff[o0 + i];
    #pragma unroll
    for (int j = 0; j < 4; j++) acc[i][j] = bia;
  }

  const float* xb = x + ((size_t)b * Cc) * NPIX + p0;
  for (int c0 = 0; c0 < Cc; c0 += 32) {
    __syncthreads();
    for (int f = tid; f < 1024; f += 256) {          // 32x128 floats as float4
      int c = f >> 5, pq = f & 31;
      ((float4*)Xs[c])[pq] = *(const float4*)(xb + (size_t)(c0 + c) * NPIX + pq * 4);
    }
    for (int e = tid; e < 2048; e += 256) {          // Ws[ci][o]
      int o = e & 63, ci = e >> 6;
      Ws[ci][o] = Weff[o * Cc + c0 + ci];
    }
    __syncthreads();
    #pragma unroll
    for (int c = 0; c < 32; c++) {
      float4 xv = ((const float4*)Xs[c])[tx];
      float4 w0 = ((const float4*)Ws[c])[ty * 2];
      float4 w1 = ((const float4*)Ws[c])[ty * 2 + 1];
      float xa[4] = {xv.x, xv.y, xv.z, xv.w};
      float wa[8] = {w0.x, w0.y, w0.z, w0.w, w1.x, w1.y, w1.z, w1.w};
      #pragma unroll
      for (int i = 0; i < 8; i++)
        #pragma unroll
        for (int j = 0; j < 4; j++) acc[i][j] += wa[i] * xa[j];
    }
  }
  float* op = xred + ((size_t)b * RED) * NPIX + p0 + tx * 4;
  #pragma unroll
  for (int i = 0; i < 8; i++) {
    *(float4*)(op + (size_t)(o0 + i) * NPIX) =
        make_float4(acc[i][0], acc[i][1], acc[i][2], acc[i][3]);
  }
}

// ---------------------------------------------------------------------------
// Kernel B: per-window attention. One block (256 thr) per 8x8 window.
// Window w: b = w>>8, wh = (w>>4)&15, ww = w&15. Tokens n = i*8+j (64).
// ---------------------------------------------------------------------------
__global__ __launch_bounds__(256) void attn_kernel(
    const float* __restrict__ xred,
    const float* __restrict__ qk_base_w, const float* __restrict__ q_head_w,
    const float* __restrict__ q_head_b,  const float* __restrict__ k_head_w,
    const float* __restrict__ k_head_b,  const float* __restrict__ v_w,
    const float* __restrict__ v_b,       const float* __restrict__ o_w,
    const float* __restrict__ o_b,       float* __restrict__ yout) {
  __shared__ float smem[13952];
  float* Xw    = smem;          // 64r x 64n = 4096   (reused as outT 64x33 later)
  float* base_ = smem + 4096;   // 32m x 64n = 2048
  float* kT    = smem + 6144;   // 64n x 33  = 2112 (padded)
  float* vT    = smem + 8256;   // 2112
  float* qkw   = smem + 10368;  // 512
  float* vw    = smem + 10880;  // 512
  float* ow    = smem + 11392;  // 512
  float* qhw   = smem + 11904;  // 1024
  float* khw   = smem + 12928;  // 1024
  float* outT  = smem;          // alias of Xw (safe: Xw dead after S3)

  const int w  = blockIdx.x;
  const int b  = w >> 8;
  const int wh = (w >> 4) & 15, wwi = w & 15;
  const int tid = threadIdx.x;
  const float* xb = xred + ((size_t)b * RED) * NPIX + (wh * 8) * Ww + wwi * 8;

  // S1: stage window + weights
  for (int e = tid; e < 4096; e += 256) {
    int r = e >> 6, n = e & 63;
    Xw[e] = xb[(size_t)r * NPIX + (n >> 3) * Ww + (n & 7)];
  }
  for (int e = tid; e < 512; e += 256) { qkw[e] = qk_base_w[e]; vw[e] = v_w[e]; ow[e] = o_w[e]; }
  for (int e = tid; e < 1024; e += 256) { qhw[e] = q_head_w[e]; khw[e] = k_head_w[e]; }
  __syncthreads();

  // S2: base[m][n] = sum_{i<16} qkw[g,m%8,i] * Xw[g*16+i][n]
  for (int e = tid; e < 2048; e += 256) {
    int m = e >> 6, n = e & 63, g = m >> 3;
    const float* wp = qkw + (g * 8 + (m & 7)) * 16;
    const float* xp = Xw + g * 16 * 64 + n;
    float a = 0.f;
    #pragma unroll
    for (int i = 0; i < 16; i++) a += wp[i] * xp[i * 64];
    base_[e] = a;
  }
  __syncthreads();

  // S3: kT[n][m] (head matmul K=32), vT[n][m] (grouped conv K=16)
  for (int e = tid; e < 2048; e += 256) {
    int m = e >> 6, n = e & 63, g = m >> 3;
    float a = k_head_b[m];
    const float* wp = khw + m * 32;
    #pragma unroll
    for (int i = 0; i < 32; i++) a += wp[i] * base_[i * 64 + n];
    kT[n * 33 + m] = a;
    float av = v_b[m];
    const float* vp = vw + (g * 8 + (m & 7)) * 16;
    const float* xp = Xw + g * 16 * 64 + n;
    #pragma unroll
    for (int i = 0; i < 16; i++) av += vp[i] * xp[i * 64];
    vT[n * 33 + m] = av;
  }
  __syncthreads();

  // S4: one thread per (head h, query token n)
  const int h = tid >> 6, n = tid & 63;
  float qv[8];
  {
    float a[8];
    #pragma unroll
    for (int d = 0; d < 8; d++) a[d] = q_head_b[h * 8 + d];
    #pragma unroll
    for (int i = 0; i < 32; i++) {
      float bv = base_[i * 64 + n];
      #pragma unroll
      for (int d = 0; d < 8; d++) a[d] += qhw[(h * 8 + d) * 32 + i] * bv;
    }
    #pragma unroll
    for (int d = 0; d < 8; d++) qv[d] = a[d] * SCALE;
  }
  float s[64];
  float mx = -1e30f;
  const float* kTh = kT + h * 8;
  #pragma unroll
  for (int j = 0; j < 64; j++) {
    const float* kr = kTh + j * 33;
    float a = 0.f;
    #pragma unroll
    for (int d = 0; d < 8; d++) a += qv[d] * kr[d];
    s[j] = a;
    mx = fmaxf(mx, a);
  }
  float sum = 0.f;
  #pragma unroll
  for (int j = 0; j < 64; j++) { float e = __expf(s[j] - mx); s[j] = e; sum += e; }
  float inv = 1.0f / sum;
  float o[8] = {0, 0, 0, 0, 0, 0, 0, 0};
  const float* vTh = vT + h * 8;
  #pragma unroll
  for (int j = 0; j < 64; j++) {
    float p = s[j];
    const float* vr = vTh + j * 33;
    #pragma unroll
    for (int d = 0; d < 8; d++) o[d] += p * vr[d];
  }
  __syncthreads();  // all Xw/base/kT/vT consumption done before outT (=Xw) write
  #pragma unroll
  for (int d = 0; d < 8; d++) outT[n * 33 + h * 8 + d] = o[d] * inv;
  __syncthreads();

  // S5: y[r][n] = o_b[r] + sum_{j<8} o_w[g',r%16,j] * outT[n][g'*8+j]
  float* yb = yout + ((size_t)b * RED) * NPIX + (wh * 8) * Ww + wwi * 8;
  for (int e = tid; e < 4096; e += 256) {
    int r = e >> 6, nn = e & 63, g = r >> 4;
    float a = o_b[r];
    const float* wp = ow + (g * 16 + (r & 15)) * 8;
    const float* op = outT + nn * 33 + g * 8;
    #pragma unroll
    for (int j = 0; j < 8; j++) a += wp[j] * op[j];
    yb[(size_t)r * NPIX + (nn >> 3) * Ww + (nn & 7)] = a;
  }
}

// ---------------------------------------------------------------------------
// Kernel C: out[b,co,p] = x[b,co,p] + beff_out[co] + sum_r Weff_out[co,r]*y[b,r,p]
// Tile: 64 co x 128 positions, K=64 in one LDS pass. Fused residual.
// ---------------------------------------------------------------------------
__global__ __launch_bounds__(256) void outproj_kernel(
    const float* __restrict__ y, const float* __restrict__ Weff,
    const float* __restrict__ beff, const float* __restrict__ x,
    float* __restrict__ out) {
  __shared__ float Ys[64][128];
  __shared__ float Ws[64][64];
  const int b   = blockIdx.z;
  const int co0 = blockIdx.y * 64;
  const int p0  = blockIdx.x * 128;
  const int tid = threadIdx.x;
  const int tx = tid & 31, ty = tid >> 5;
  const int ol = ty * 8;

  const float* yb = y + ((size_t)b * RED) * NPIX + p0;
  for (int f = tid; f < 2048; f += 256) {  // 64x128 floats as float4
    int r = f >> 5, pq = f & 31;
    ((float4*)Ys[r])[pq] = *(const float4*)(yb + (size_t)r * NPIX + pq * 4);
  }
  for (int e = tid; e < 4096; e += 256) {  // Ws[r][co]
    int co = e & 63, r = e >> 6;
    Ws[r][co] = Weff[(size_t)(co0 + co) * RED + r];
  }
  __syncthreads();

  float acc[8][4];
  #pragma unroll
  for (int i = 0; i < 8; i++) {
    float bia = beff[co0 + ol + i];
    #pragma unroll
    for (int j = 0; j < 4; j++) acc[i][j] = bia;
  }
  #pragma unroll
  for (int r = 0; r < 64; r++) {
    float4 xv = ((const float4*)Ys[r])[tx];
    float4 w0 = ((const float4*)Ws[r])[ty * 2];
    float4 w1 = ((const float4*)Ws[r])[ty * 2 + 1];
    float xa[4] = {xv.x, xv.y, xv.z, xv.w};
    float wa[8] = {w0.x, w0.y, w0.z, w0.w, w1.x, w1.y, w1.z, w1.w};
    #pragma unroll
    for (int i = 0; i < 8; i++)
      #pragma unroll
      for (int j = 0; j < 4; j++) acc[i][j] += wa[i] * xa[j];
  }

  const float* xb = x + ((size_t)b * Cc + co0) * NPIX + p0 + tx * 4;
  float* ob = out + ((size_t)b * Cc + co0) * NPIX + p0 + tx * 4;
  #pragma unroll
  for (int i = 0; i < 8; i++) {
    float4 xv = *(const float4*)(xb + (size_t)(ol + i) * NPIX);
    *(float4*)(ob + (size_t)(ol + i) * NPIX) =
        make_float4(acc[i][0] + xv.x, acc[i][1] + xv.y,
                    acc[i][2] + xv.z, acc[i][3] + xv.w);
  }
}

// ---------------------------------------------------------------------------
extern "C" void kernel_launch(void* const* d_in, const int* in_sizes, int n_in,
                              void* d_out, int out_size, void* d_ws, size_t ws_size,
                              hipStream_t stream) {
  const float* x           = (const float*)d_in[0];
  const float* bn_in_gamma = (const float*)d_in[1];
  const float* bn_in_beta  = (const float*)d_in[2];
  const float* bn_in_mean  = (const float*)d_in[3];
  const float* bn_in_var   = (const float*)d_in[4];
  const float* in_proj_w   = (const float*)d_in[5];
  const float* qk_base_w   = (const float*)d_in[6];
  const float* q_head_w    = (const float*)d_in[7];
  const float* q_head_b    = (const float*)d_in[8];
  const float* k_head_w    = (const float*)d_in[9];
  const float* k_head_b    = (const float*)d_in[10];
  const float* v_w         = (const float*)d_in[11];
  const float* v_b         = (const float*)d_in[12];
  const float* o_w         = (const float*)d_in[13];
  const float* o_b         = (const float*)d_in[14];
  const float* out_proj_w  = (const float*)d_in[15];
  const float* bn_out_gamma= (const float*)d_in[16];
  const float* bn_out_beta = (const float*)d_in[17];
  const float* bn_out_mean = (const float*)d_in[18];
  const float* bn_out_var  = (const float*)d_in[19];
  const float* alpha       = (const float*)d_in[20];

  float* ws = (float*)d_ws;
  float* Weff_in  = ws;                      // 64*256  = 16384
  float* beff_in  = Weff_in + 16384;         // 64
  float* Weff_out = beff_in + 64;            // 256*64  = 16384
  float* beff_out = Weff_out + 16384;        // 256
  float* xred     = beff_out + 256;          // 16*64*16384 = 16777216
  float* ybuf     = xred + (size_t)16777216; // 16777216
  (void)ws_size; (void)in_sizes; (void)n_in; (void)out_size;

  prep_kernel<<<64, 256, 0, stream>>>(
      bn_in_gamma, bn_in_beta, bn_in_mean, bn_in_var, in_proj_w,
      out_proj_w, bn_out_gamma, bn_out_beta, bn_out_mean, bn_out_var,
      alpha, Weff_in, beff_in, Weff_out, beff_out);

  inproj_kernel<<<dim3(128, 16), 256, 0, stream>>>(x, Weff_in, beff_in, xred);

  attn_kernel<<<4096, 256, 0, stream>>>(
      xred, qk_base_w, q_head_w, q_head_b, k_head_w, k_head_b,
      v_w, v_b, o_w, o_b, ybuf);

  outproj_kernel<<<dim3(128, 4, 16), 256, 0, stream>>>(
      ybuf, Weff_out, beff_out, x, (float*)d_out);
}